// Round 6
// baseline (414.873 us; speedup 1.0000x reference)
//
#include <hip/hip_runtime.h>
#include <hip/hip_bf16.h>

#define H 128
#define NSTEPS 8
#define DT_MAXF 0.125f
#define WAVES 4
#define PPW 16            // points per wave (one 16x16 MFMA N-tile)
#define PPB (WAVES*PPW)   // 64 points per block

typedef __attribute__((ext_vector_type(8))) short short8;   // 8 bf16 MFMA A/B frag
typedef __attribute__((ext_vector_type(4))) float floatx4;  // MFMA C/D frag
typedef __attribute__((ext_vector_type(2))) float f32x2;    // packed-FP32 pair (v_pk_*_f32)

__device__ __forceinline__ f32x2 sp2(float v) { return (f32x2){v, v}; }
__device__ __forceinline__ f32x2 fma2(f32x2 a, f32x2 b, f32x2 c) {
    return __builtin_elementwise_fma(a, b, c);              // -> v_pk_fma_f32
}
// identical math to scalar fast_tanh per half: e=exp2(x*2log2e); r=rcp(e+1); 1-2r
__device__ __forceinline__ f32x2 tanh2(f32x2 x) {
    f32x2 y = x * 2.8853900817779268f;
    f32x2 e; e[0] = __builtin_amdgcn_exp2f(y[0]); e[1] = __builtin_amdgcn_exp2f(y[1]);
    f32x2 ep = e + 1.0f;
    f32x2 r; r[0] = __builtin_amdgcn_rcpf(ep[0]); r[1] = __builtin_amdgcn_rcpf(ep[1]);
    return fma2(sp2(-2.0f), r, sp2(1.0f));
}
__device__ __forceinline__ unsigned f2bf(float x) {           // fp32 -> bf16 bits, RNE
    unsigned u = __float_as_uint(x);
    return (u + 0x7FFFu + ((u >> 16) & 1u)) >> 16;
}
__device__ __forceinline__ unsigned pk2(float a, float b) {   // packed bf16 cvt
    union { __hip_bfloat162 h; unsigned u; } U;
    U.h = __float22bfloat162_rn(make_float2(a, b));
    return U.u;
}
__device__ __forceinline__ unsigned pkv(f32x2 v) { return pk2(v[0], v[1]); }
__device__ __forceinline__ short8 mk8(unsigned a, unsigned b, unsigned c, unsigned d) {
    union { unsigned u[4]; short8 s; } U;
    U.u[0] = a; U.u[1] = b; U.u[2] = c; U.u[3] = d; return U.s;
}
// xyzt B-frag, hi/lo split bf16. Lane q=0 carries hi+lo, q=1 carries hi, q>=2 zero.
__device__ __forceinline__ short8 xyzt_frag(float x, float y, float z, float t, int q) {
    unsigned hx = f2bf(x), hy = f2bf(y), hz = f2bf(z), ht = f2bf(t);
    float lx = x - __uint_as_float(hx << 16);
    float ly = y - __uint_as_float(hy << 16);
    float lz = z - __uint_as_float(hz << 16);
    float lt = t - __uint_as_float(ht << 16);
    unsigned w0 = hx | (hy << 16), w1 = hz | (ht << 16);
    unsigned w2 = pk2(lx, ly),     w3 = pk2(lz, lt);
    union { unsigned u[4]; short8 s; } F;
    F.u[0] = (q < 2)  ? w0 : 0u;
    F.u[1] = (q < 2)  ? w1 : 0u;
    F.u[2] = (q == 0) ? w2 : 0u;
    F.u[3] = (q == 0) ? w3 : 0u;
    return F.s;
}

// R12: L1/L2/L3 contractions all on the MFMA pipe (pi-permuted k so C/D
// layout == own B-slots; zero cross-lane repack). 378 us, occupancy 21%.
// R13/R14 lesson: rocprof VGPR_Count excludes AGPRs; true per-lane total is
// ~195 regs -> 2 waves/SIMD is the REGISTER binder (not LDS). Budget 128
// (R13) spilled catastrophically; natural (R14) stayed at 2 waves.
// R15: target the 168-reg / 3-waves/SIMD point:
//   - quarter-split the L2/L3 nest: each quarter = one L3 slice = 2 output
//     tiles x 4 chains. Acc live 64 -> 32; s2 consumed in-quarter. Peak
//     ~195 -> ~160. Quarter == L3 slice, so MFMA operand values and
//     accumulation order are IDENTICAL to R12 -> bitwise-same output.
//   - __launch_bounds__(256,3): 168-reg budget, 3 blocks/CU (LDS 47104x3
//     = 141KB <= 160KB fits).
//   - revert R14's LDS diet (cost 5%, bought nothing).
// Containment: sched_barrier(0) after each phase (r9 lesson).
__global__ __launch_bounds__(256, 3)
void velwarp(const float* __restrict__ code, const float* __restrict__ pos,
             const float* __restrict__ t1g, const float* __restrict__ t2g,
             const float* __restrict__ W1, const float* __restrict__ b1,
             const float* __restrict__ W2, const float* __restrict__ b2,
             const float* __restrict__ W3, const float* __restrict__ b3,
             float* __restrict__ out, int N)
{
    __shared__ __align__(16) uint4 WbufU[2048];   // 32KB: W1 fp32 staging (init) then W2 bf16 frags
    __shared__ __align__(16) uint4 W1AU[8*64];    // 8KB : layer-1 A-frags (xyzt rows, hi/lo split)
    __shared__ __align__(16) uint4 W3AU[4*64];    // 4KB : layer-3 A-frags (W3^T, pi-permuted)
    __shared__ __align__(16) floatx4 WdX4[32];    // W1[64][u] in C/D order (= row-linear)
    __shared__ __align__(16) floatx4 WdY4[32];    // W1[65][u]
    __shared__ __align__(16) floatx4 WdZ4[32];    // W1[66][u]
    __shared__ __align__(16) floatx4 b2C4[32];    // b2 in C/D order

    const int tid = threadIdx.x;
    const int L   = tid & 63;
    const int m   = L & 15;      // this lane's point (C/D col)
    const int q   = L >> 4;      // C/D row group = q*4+reg; B-frag k-quad
    const int pb  = blockIdx.x * PPB + (tid >> 6) * PPW;
    const int p   = pb + m;      // global point index

    // ---- stage W1 rows [0:64) as fp32 into Wbuf
    {
        const float4* s4 = (const float4*)W1;
        float4* d4 = (float4*)WbufU;
        #pragma unroll 4
        for (int i = tid; i < (64*H)/4; i += 256) d4[i] = s4[i];
    }
    // ---- layer-1 A-frags: tile t, lane l: row u = 16t+(l&15); hi/lo split
    for (int e = tid; e < 512; e += 256) {
        int t = e >> 6, l = e & 63;
        int u = t*16 + (l & 15), qq = l >> 4;
        unsigned hb[4], lb[4];
        #pragma unroll
        for (int c = 0; c < 4; ++c) {
            float wv = W1[(64 + c)*H + u];
            unsigned hh = f2bf(wv);
            float wl = wv - __uint_as_float(hh << 16);
            hb[c] = hh; lb[c] = f2bf(wl);
        }
        unsigned hi01 = hb[0] | (hb[1] << 16), hi23 = hb[2] | (hb[3] << 16);
        unsigned lo01 = lb[0] | (lb[1] << 16), lo23 = lb[2] | (lb[3] << 16);
        uint4 o;
        if (qq == 0)      o = make_uint4(hi01, hi23, hi01, hi23);
        else if (qq == 1) o = make_uint4(lo01, lo23, 0u, 0u);
        else              o = make_uint4(0u, 0u, 0u, 0u);
        W1AU[e] = o;
    }
    // ---- layer-3 A-frags: slice s, lane l: row a = l&15 (rows 3..15 zero)
    for (int e = tid; e < 256; e += 256) {
        int s = e >> 6, l = e & 63;
        int a = l & 15, qq = l >> 4;
        uint4 o = make_uint4(0u, 0u, 0u, 0u);
        if (a < 3) {
            int u0 = s*32 + qq*4, u1 = u0 + 16;
            o.x = f2bf(W3[(u0+0)*3+a]) | (f2bf(W3[(u0+1)*3+a]) << 16);
            o.y = f2bf(W3[(u0+2)*3+a]) | (f2bf(W3[(u0+3)*3+a]) << 16);
            o.z = f2bf(W3[(u1+0)*3+a]) | (f2bf(W3[(u1+1)*3+a]) << 16);
            o.w = f2bf(W3[(u1+2)*3+a]) | (f2bf(W3[(u1+3)*3+a]) << 16);
        }
        W3AU[e] = o;
    }
    if (tid < 32) {
        WdX4[tid] = ((const floatx4*)(W1 + (size_t)64*H))[tid];
        WdY4[tid] = ((const floatx4*)(W1 + (size_t)65*H))[tid];
        WdZ4[tid] = ((const floatx4*)(W1 + (size_t)66*H))[tid];
        b2C4[tid] = ((const floatx4*)b2)[tid];
    }
    __syncthreads();

    // ---- base1C[t] (fp32, C/D layout): u = 16t + 4q + reg
    floatx4 base1C[8];
    {
        #pragma unroll
        for (int t = 0; t < 8; ++t) base1C[t] = *(const floatx4*)&b1[t*16 + q*4];
        const float* Ws = (const float*)WbufU;
        const float* crow = code + (size_t)p * 64;
        for (int i = 0; i < 64; ++i) {
            f32x2 c = sp2(crow[i]);
            #pragma unroll
            for (int t = 0; t < 8; ++t) {
                floatx4 wq = *(const floatx4*)&Ws[i*H + t*16 + q*4];
                base1C[t].xy = fma2(c, wq.xy, base1C[t].xy);
                base1C[t].zw = fma2(c, wq.zw, base1C[t].zw);
            }
        }
    }
    __syncthreads();   // all lanes done reading W1 fp32 before repack

    // ---- pack W2 -> bf16 A-frags with pi-permuted k
    for (int ch = tid; ch < 2048; ch += 256) {
        int ln = ch & 63, ts = ch >> 6;
        int s = ts & 3, t = ts >> 2;
        int qq = ln >> 4, n = t*16 + (ln & 15);
        int u0 = s*32 + qq*4, u1 = u0 + 16;
        unsigned w0 = f2bf(W2[(u0+0)*H+n]) | (f2bf(W2[(u0+1)*H+n]) << 16);
        unsigned w1 = f2bf(W2[(u0+2)*H+n]) | (f2bf(W2[(u0+3)*H+n]) << 16);
        unsigned w2 = f2bf(W2[(u1+0)*H+n]) | (f2bf(W2[(u1+1)*H+n]) << 16);
        unsigned w3v = f2bf(W2[(u1+2)*H+n]) | (f2bf(W2[(u1+3)*H+n]) << 16);
        WbufU[ch] = make_uint4(w0, w1, w2, w3v);
    }

    // ---- per-lane point state
    float px_ = pos[p*3+0], py_ = pos[p*3+1], pz_ = pos[p*3+2];
    float tc_ = t1g[p];
    float off_ = tc_ - t2g[p];
    float D[9];
    #pragma unroll
    for (int j = 0; j < 9; ++j) D[j] = (j==0||j==4||j==8) ? 1.0f : 0.0f;
    const float b30 = b3[0], b31 = b3[1], b32 = b3[2];
    __syncthreads();

    const short8* Bf   = (const short8*)WbufU;
    const short8* W1Af = (const short8*)W1AU;
    const short8* W3Af = (const short8*)W3AU;
    const floatx4 Z4 = {0.f, 0.f, 0.f, 0.f};

    for (int step = 0; step < NSTEPS; ++step) {
        // ======== eval A: v(x,t) ========
        float vAx, vAy, vAz;
        {
            short8 xf = xyzt_frag(px_, py_, pz_, tc_, q);
            floatx4 z[8];
            #pragma unroll
            for (int t = 0; t < 8; ++t)
                z[t] = __builtin_amdgcn_mfma_f32_16x16x32_bf16(W1Af[t*64 + L], xf, base1C[t], 0, 0, 0);
            __builtin_amdgcn_sched_barrier(0);
            short8 fh[4];
            #pragma unroll
            for (int s = 0; s < 4; ++s) {
                f32x2 a0 = tanh2(z[2*s].xy),   a1 = tanh2(z[2*s].zw);
                f32x2 c0 = tanh2(z[2*s+1].xy), c1 = tanh2(z[2*s+1].zw);
                fh[s] = mk8(pkv(a0), pkv(a1), pkv(c0), pkv(c1));
            }
            __builtin_amdgcn_sched_barrier(0);
            // quarter qi covers tiles 2qi,2qi+1 == L3 slice qi
            floatx4 vacc = Z4;
            #pragma unroll
            for (int qi = 0; qi < 4; ++qi) {
                const int T0 = 2*qi, T1 = 2*qi + 1;
                floatx4 acc0 = __builtin_amdgcn_mfma_f32_16x16x32_bf16(
                    Bf[(T0*4 + 0)*64 + L], fh[0], b2C4[T0*4 + q], 0, 0, 0);
                floatx4 acc1 = __builtin_amdgcn_mfma_f32_16x16x32_bf16(
                    Bf[(T1*4 + 0)*64 + L], fh[0], b2C4[T1*4 + q], 0, 0, 0);
                #pragma unroll
                for (int s = 1; s < 4; ++s) {
                    acc0 = __builtin_amdgcn_mfma_f32_16x16x32_bf16(Bf[(T0*4 + s)*64 + L], fh[s], acc0, 0, 0, 0);
                    acc1 = __builtin_amdgcn_mfma_f32_16x16x32_bf16(Bf[(T1*4 + s)*64 + L], fh[s], acc1, 0, 0, 0);
                }
                __builtin_amdgcn_sched_barrier(0);
                f32x2 e00 = tanh2(acc0.xy), e01 = tanh2(acc0.zw);
                f32x2 e10 = tanh2(acc1.xy), e11 = tanh2(acc1.zw);
                short8 ef = mk8(pkv(e00), pkv(e01), pkv(e10), pkv(e11));
                vacc = __builtin_amdgcn_mfma_f32_16x16x32_bf16(W3Af[qi*64 + L], ef, vacc, 0, 0, 0);
                __builtin_amdgcn_sched_barrier(0);
            }
            vAx = __shfl(vacc[0], m, 64);
            vAy = __shfl(vacc[1], m, 64);
            vAz = __shfl(vacc[2], m, 64);
        }

        float dt_ = copysignf(fminf(fabsf(off_), DT_MAXF), off_);
        float hd = 0.5f * dt_;
        float mx = px_ - hd*(vAx + b30);
        float my = py_ - hd*(vAy + b31);
        float mz = pz_ - hd*(vAz + b32);
        float tm = tc_ - hd;

        // ======== eval B: v + Jacobian at midpoint ========
        float vx, vy, vz, Jr[9];
        {
            short8 xf = xyzt_frag(mx, my, mz, tm, q);
            floatx4 z[8];
            #pragma unroll
            for (int t = 0; t < 8; ++t)
                z[t] = __builtin_amdgcn_mfma_f32_16x16x32_bf16(W1Af[t*64 + L], xf, base1C[t], 0, 0, 0);
            __builtin_amdgcn_sched_barrier(0);
            short8 fh[4], fd0[4], fd1[4], fd2[4];
            #pragma unroll
            for (int s = 0; s < 4; ++s) {
                unsigned uh[4], u0[4], u1[4], u2[4];
                #pragma unroll
                for (int hf = 0; hf < 2; ++hf) {
                    int t = 2*s + hf;
                    f32x2 h0 = tanh2(z[t].xy), h1 = tanh2(z[t].zw);
                    f32x2 s0 = fma2(-h0, h0, sp2(1.0f));
                    f32x2 s1 = fma2(-h1, h1, sp2(1.0f));
                    floatx4 wx = WdX4[t*4 + q], wy = WdY4[t*4 + q], wz = WdZ4[t*4 + q];
                    uh[2*hf+0] = pkv(h0);         uh[2*hf+1] = pkv(h1);
                    u0[2*hf+0] = pkv(s0 * wx.xy); u0[2*hf+1] = pkv(s1 * wx.zw);
                    u1[2*hf+0] = pkv(s0 * wy.xy); u1[2*hf+1] = pkv(s1 * wy.zw);
                    u2[2*hf+0] = pkv(s0 * wz.xy); u2[2*hf+1] = pkv(s1 * wz.zw);
                }
                fh[s]  = mk8(uh[0], uh[1], uh[2], uh[3]);
                fd0[s] = mk8(u0[0], u0[1], u0[2], u0[3]);
                fd1[s] = mk8(u1[0], u1[1], u1[2], u1[3]);
                fd2[s] = mk8(u2[0], u2[1], u2[2], u2[3]);
            }
            __builtin_amdgcn_sched_barrier(0);
            // quarter qi = one L3 slice: tiles 2qi,2qi+1, all 4 chains, post,
            // 4 L3 MFMAs. Acc live = 8 quads (was 16); s2 consumed in-quarter.
            floatx4 V = Z4, J0 = Z4, J1 = Z4, J2 = Z4;
            #pragma unroll
            for (int qi = 0; qi < 4; ++qi) {
                const int T0 = 2*qi, T1 = 2*qi + 1;
                floatx4 aH0, aH1, aD00, aD01, aD10, aD11, aD20, aD21;
                {
                    short8 A0 = Bf[(T0*4 + 0)*64 + L];
                    short8 A1 = Bf[(T1*4 + 0)*64 + L];
                    aH0  = __builtin_amdgcn_mfma_f32_16x16x32_bf16(A0, fh[0],  b2C4[T0*4 + q], 0, 0, 0);
                    aH1  = __builtin_amdgcn_mfma_f32_16x16x32_bf16(A1, fh[0],  b2C4[T1*4 + q], 0, 0, 0);
                    aD00 = __builtin_amdgcn_mfma_f32_16x16x32_bf16(A0, fd0[0], Z4, 0, 0, 0);
                    aD01 = __builtin_amdgcn_mfma_f32_16x16x32_bf16(A1, fd0[0], Z4, 0, 0, 0);
                    aD10 = __builtin_amdgcn_mfma_f32_16x16x32_bf16(A0, fd1[0], Z4, 0, 0, 0);
                    aD11 = __builtin_amdgcn_mfma_f32_16x16x32_bf16(A1, fd1[0], Z4, 0, 0, 0);
                    aD20 = __builtin_amdgcn_mfma_f32_16x16x32_bf16(A0, fd2[0], Z4, 0, 0, 0);
                    aD21 = __builtin_amdgcn_mfma_f32_16x16x32_bf16(A1, fd2[0], Z4, 0, 0, 0);
                }
                __builtin_amdgcn_sched_barrier(0);
                #pragma unroll
                for (int s = 1; s < 4; ++s) {
                    short8 A0 = Bf[(T0*4 + s)*64 + L];
                    short8 A1 = Bf[(T1*4 + s)*64 + L];
                    aH0  = __builtin_amdgcn_mfma_f32_16x16x32_bf16(A0, fh[s],  aH0,  0, 0, 0);
                    aH1  = __builtin_amdgcn_mfma_f32_16x16x32_bf16(A1, fh[s],  aH1,  0, 0, 0);
                    aD00 = __builtin_amdgcn_mfma_f32_16x16x32_bf16(A0, fd0[s], aD00, 0, 0, 0);
                    aD01 = __builtin_amdgcn_mfma_f32_16x16x32_bf16(A1, fd0[s], aD01, 0, 0, 0);
                    aD10 = __builtin_amdgcn_mfma_f32_16x16x32_bf16(A0, fd1[s], aD10, 0, 0, 0);
                    aD11 = __builtin_amdgcn_mfma_f32_16x16x32_bf16(A1, fd1[s], aD11, 0, 0, 0);
                    aD20 = __builtin_amdgcn_mfma_f32_16x16x32_bf16(A0, fd2[s], aD20, 0, 0, 0);
                    aD21 = __builtin_amdgcn_mfma_f32_16x16x32_bf16(A1, fd2[s], aD21, 0, 0, 0);
                    __builtin_amdgcn_sched_barrier(0);
                }
                // post for this slice: h2/s2/dd -> e-frags -> 4 L3 MFMAs
                f32x2 h0 = tanh2(aH0.xy), h1 = tanh2(aH0.zw);
                f32x2 h2v = tanh2(aH1.xy), h3 = tanh2(aH1.zw);
                f32x2 s0 = fma2(-h0, h0, sp2(1.0f));
                f32x2 s1 = fma2(-h1, h1, sp2(1.0f));
                f32x2 s2v = fma2(-h2v, h2v, sp2(1.0f));
                f32x2 s3 = fma2(-h3, h3, sp2(1.0f));
                short8 eh = mk8(pkv(h0), pkv(h1), pkv(h2v), pkv(h3));
                short8 e0 = mk8(pkv(s0*aD00.xy), pkv(s1*aD00.zw), pkv(s2v*aD01.xy), pkv(s3*aD01.zw));
                short8 e1 = mk8(pkv(s0*aD10.xy), pkv(s1*aD10.zw), pkv(s2v*aD11.xy), pkv(s3*aD11.zw));
                short8 e2 = mk8(pkv(s0*aD20.xy), pkv(s1*aD20.zw), pkv(s2v*aD21.xy), pkv(s3*aD21.zw));
                const short8 WA = W3Af[qi*64 + L];
                V  = __builtin_amdgcn_mfma_f32_16x16x32_bf16(WA, eh, V,  0, 0, 0);
                J0 = __builtin_amdgcn_mfma_f32_16x16x32_bf16(WA, e0, J0, 0, 0, 0);
                J1 = __builtin_amdgcn_mfma_f32_16x16x32_bf16(WA, e1, J1, 0, 0, 0);
                J2 = __builtin_amdgcn_mfma_f32_16x16x32_bf16(WA, e2, J2, 0, 0, 0);
                __builtin_amdgcn_sched_barrier(0);
            }
            vx = __shfl(V[0], m, 64) + b30;
            vy = __shfl(V[1], m, 64) + b31;
            vz = __shfl(V[2], m, 64) + b32;
            Jr[0] = __shfl(J0[0], m, 64); Jr[1] = __shfl(J1[0], m, 64); Jr[2] = __shfl(J2[0], m, 64);
            Jr[3] = __shfl(J0[1], m, 64); Jr[4] = __shfl(J1[1], m, 64); Jr[5] = __shfl(J2[1], m, 64);
            Jr[6] = __shfl(J0[2], m, 64); Jr[7] = __shfl(J1[2], m, 64); Jr[8] = __shfl(J2[2], m, 64);
        }

        // def + state update, replicated identically in all lanes (inputs broadcast)
        float nd[9];
        #pragma unroll
        for (int o = 0; o < 3; ++o)
            #pragma unroll
            for (int c = 0; c < 3; ++c)
                nd[o*3+c] = D[o*3+c] - dt_*(Jr[o*3+0]*D[0*3+c] + Jr[o*3+1]*D[1*3+c] + Jr[o*3+2]*D[2*3+c]);
        #pragma unroll
        for (int j = 0; j < 9; ++j) D[j] = nd[j];
        px_ = fmaf(-dt_, vx, px_);
        py_ = fmaf(-dt_, vy, py_);
        pz_ = fmaf(-dt_, vz, pz_);
        tc_  -= dt_;
        off_ -= dt_;
    }

    // ---- output: q==0 lane of each point writes xyz + deform
    if (q == 0) {
        out[p*3+0] = px_; out[p*3+1] = py_; out[p*3+2] = pz_;
        float* o9 = out + (size_t)N*3 + (size_t)p*9;
        #pragma unroll
        for (int j = 0; j < 9; ++j) o9[j] = D[j];
    }
}

extern "C" void kernel_launch(void* const* d_in, const int* in_sizes, int n_in,
                              void* d_out, int out_size, void* d_ws, size_t ws_size,
                              hipStream_t stream) {
    const float* code = (const float*)d_in[0];
    const float* pos  = (const float*)d_in[1];
    const float* t1   = (const float*)d_in[2];
    const float* t2   = (const float*)d_in[3];
    const float* W1   = (const float*)d_in[4];
    const float* b1   = (const float*)d_in[5];
    const float* W2   = (const float*)d_in[6];
    const float* b2   = (const float*)d_in[7];
    const float* W3   = (const float*)d_in[8];
    const float* b3   = (const float*)d_in[9];
    float* out = (float*)d_out;
    const int N = in_sizes[1] / 3;           // 131072
    const int blocks = N / PPB;              // 2048
    velwarp<<<blocks, 256, 0, stream>>>(code, pos, t1, t2, W1, b1, W2, b2, W3, b3, out, N);
}

// Round 7
// 400.805 us; speedup vs baseline: 1.0351x; 1.0351x over previous
//
#include <hip/hip_runtime.h>
#include <hip/hip_bf16.h>

#define H 128
#define NSTEPS 8
#define DT_MAXF 0.125f
#define WAVES 4
#define PPW 16            // points per wave (one 16x16 MFMA N-tile)
#define PPB (WAVES*PPW)   // 64 points per block

typedef __attribute__((ext_vector_type(8))) short short8;   // 8 bf16 MFMA A/B frag
typedef __attribute__((ext_vector_type(4))) float floatx4;  // MFMA C/D frag
typedef __attribute__((ext_vector_type(2))) float f32x2;    // packed-FP32 pair (v_pk_*_f32)

__device__ __forceinline__ f32x2 sp2(float v) { return (f32x2){v, v}; }
__device__ __forceinline__ f32x2 fma2(f32x2 a, f32x2 b, f32x2 c) {
    return __builtin_elementwise_fma(a, b, c);              // -> v_pk_fma_f32
}
// identical math to scalar fast_tanh per half: e=exp2(x*2log2e); r=rcp(e+1); 1-2r
__device__ __forceinline__ f32x2 tanh2(f32x2 x) {
    f32x2 y = x * 2.8853900817779268f;
    f32x2 e; e[0] = __builtin_amdgcn_exp2f(y[0]); e[1] = __builtin_amdgcn_exp2f(y[1]);
    f32x2 ep = e + 1.0f;
    f32x2 r; r[0] = __builtin_amdgcn_rcpf(ep[0]); r[1] = __builtin_amdgcn_rcpf(ep[1]);
    return fma2(sp2(-2.0f), r, sp2(1.0f));
}
__device__ __forceinline__ unsigned f2bf(float x) {           // fp32 -> bf16 bits, RNE
    unsigned u = __float_as_uint(x);
    return (u + 0x7FFFu + ((u >> 16) & 1u)) >> 16;
}
__device__ __forceinline__ unsigned pk2(float a, float b) {   // packed bf16 cvt
    union { __hip_bfloat162 h; unsigned u; } U;
    U.h = __float22bfloat162_rn(make_float2(a, b));
    return U.u;
}
__device__ __forceinline__ unsigned pkv(f32x2 v) { return pk2(v[0], v[1]); }
__device__ __forceinline__ short8 mk8(unsigned a, unsigned b, unsigned c, unsigned d) {
    union { unsigned u[4]; short8 s; } U;
    U.u[0] = a; U.u[1] = b; U.u[2] = c; U.u[3] = d; return U.s;
}
// xyzt B-frag, hi/lo split bf16. Lane q=0 carries hi+lo, q=1 carries hi, q>=2 zero.
__device__ __forceinline__ short8 xyzt_frag(float x, float y, float z, float t, int q) {
    unsigned hx = f2bf(x), hy = f2bf(y), hz = f2bf(z), ht = f2bf(t);
    float lx = x - __uint_as_float(hx << 16);
    float ly = y - __uint_as_float(hy << 16);
    float lz = z - __uint_as_float(hz << 16);
    float lt = t - __uint_as_float(ht << 16);
    unsigned w0 = hx | (hy << 16), w1 = hz | (ht << 16);
    unsigned w2 = pk2(lx, ly),     w3 = pk2(lz, lt);
    union { unsigned u[4]; short8 s; } F;
    F.u[0] = (q < 2)  ? w0 : 0u;
    F.u[1] = (q < 2)  ? w1 : 0u;
    F.u[2] = (q == 0) ? w2 : 0u;
    F.u[3] = (q == 0) ? w3 : 0u;
    return F.s;
}

// R12: L1/L2/L3 contractions all on the MFMA pipe (pi-permuted k so C/D
// layout == own B-slots; zero cross-lane repack). 378 us @ 2 waves/SIMD.
// R15: quarter-split (acc 64->32 live) + (256,3) -> 3 waves BUT the 168-reg
//   budget forced spills (WRITE 6->59 MB); 390 us. KEY null result: 3 waves
//   gave the SAME VALUBusy/MfmaUtil as 2 waves -> occupancy is not the
//   binder; waves already overlap across pipes (no inter-wave barriers).
// R16: keep quarter-split (it shrinks live set, bitwise-same math), revert
//   to (256,2) -> natural spill-free allocation. If natural total <= 168
//   regs the HW gives 3 waves for free; else 2 waves == R12 fallback.
//   Also: removed the sched_barrier between the L1 MFMA block and the frag
//   build in both evals -> z[t] consumed as each L1 MFMA retires (shorter
//   z live range, MFMA||VALU overlap). All other containment kept (r9).
// Success gate: FETCH ~18.2 MB, WRITE ~6.1 MB (spill-free).
__global__ __launch_bounds__(256, 2)
void velwarp(const float* __restrict__ code, const float* __restrict__ pos,
             const float* __restrict__ t1g, const float* __restrict__ t2g,
             const float* __restrict__ W1, const float* __restrict__ b1,
             const float* __restrict__ W2, const float* __restrict__ b2,
             const float* __restrict__ W3, const float* __restrict__ b3,
             float* __restrict__ out, int N)
{
    __shared__ __align__(16) uint4 WbufU[2048];   // 32KB: W1 fp32 staging (init) then W2 bf16 frags
    __shared__ __align__(16) uint4 W1AU[8*64];    // 8KB : layer-1 A-frags (xyzt rows, hi/lo split)
    __shared__ __align__(16) uint4 W3AU[4*64];    // 4KB : layer-3 A-frags (W3^T, pi-permuted)
    __shared__ __align__(16) floatx4 WdX4[32];    // W1[64][u] in C/D order (= row-linear)
    __shared__ __align__(16) floatx4 WdY4[32];    // W1[65][u]
    __shared__ __align__(16) floatx4 WdZ4[32];    // W1[66][u]
    __shared__ __align__(16) floatx4 b2C4[32];    // b2 in C/D order

    const int tid = threadIdx.x;
    const int L   = tid & 63;
    const int m   = L & 15;      // this lane's point (C/D col)
    const int q   = L >> 4;      // C/D row group = q*4+reg; B-frag k-quad
    const int pb  = blockIdx.x * PPB + (tid >> 6) * PPW;
    const int p   = pb + m;      // global point index

    // ---- stage W1 rows [0:64) as fp32 into Wbuf
    {
        const float4* s4 = (const float4*)W1;
        float4* d4 = (float4*)WbufU;
        #pragma unroll 4
        for (int i = tid; i < (64*H)/4; i += 256) d4[i] = s4[i];
    }
    // ---- layer-1 A-frags: tile t, lane l: row u = 16t+(l&15); hi/lo split
    for (int e = tid; e < 512; e += 256) {
        int t = e >> 6, l = e & 63;
        int u = t*16 + (l & 15), qq = l >> 4;
        unsigned hb[4], lb[4];
        #pragma unroll
        for (int c = 0; c < 4; ++c) {
            float wv = W1[(64 + c)*H + u];
            unsigned hh = f2bf(wv);
            float wl = wv - __uint_as_float(hh << 16);
            hb[c] = hh; lb[c] = f2bf(wl);
        }
        unsigned hi01 = hb[0] | (hb[1] << 16), hi23 = hb[2] | (hb[3] << 16);
        unsigned lo01 = lb[0] | (lb[1] << 16), lo23 = lb[2] | (lb[3] << 16);
        uint4 o;
        if (qq == 0)      o = make_uint4(hi01, hi23, hi01, hi23);
        else if (qq == 1) o = make_uint4(lo01, lo23, 0u, 0u);
        else              o = make_uint4(0u, 0u, 0u, 0u);
        W1AU[e] = o;
    }
    // ---- layer-3 A-frags: slice s, lane l: row a = l&15 (rows 3..15 zero)
    for (int e = tid; e < 256; e += 256) {
        int s = e >> 6, l = e & 63;
        int a = l & 15, qq = l >> 4;
        uint4 o = make_uint4(0u, 0u, 0u, 0u);
        if (a < 3) {
            int u0 = s*32 + qq*4, u1 = u0 + 16;
            o.x = f2bf(W3[(u0+0)*3+a]) | (f2bf(W3[(u0+1)*3+a]) << 16);
            o.y = f2bf(W3[(u0+2)*3+a]) | (f2bf(W3[(u0+3)*3+a]) << 16);
            o.z = f2bf(W3[(u1+0)*3+a]) | (f2bf(W3[(u1+1)*3+a]) << 16);
            o.w = f2bf(W3[(u1+2)*3+a]) | (f2bf(W3[(u1+3)*3+a]) << 16);
        }
        W3AU[e] = o;
    }
    if (tid < 32) {
        WdX4[tid] = ((const floatx4*)(W1 + (size_t)64*H))[tid];
        WdY4[tid] = ((const floatx4*)(W1 + (size_t)65*H))[tid];
        WdZ4[tid] = ((const floatx4*)(W1 + (size_t)66*H))[tid];
        b2C4[tid] = ((const floatx4*)b2)[tid];
    }
    __syncthreads();

    // ---- base1C[t] (fp32, C/D layout): u = 16t + 4q + reg
    floatx4 base1C[8];
    {
        #pragma unroll
        for (int t = 0; t < 8; ++t) base1C[t] = *(const floatx4*)&b1[t*16 + q*4];
        const float* Ws = (const float*)WbufU;
        const float* crow = code + (size_t)p * 64;
        for (int i = 0; i < 64; ++i) {
            f32x2 c = sp2(crow[i]);
            #pragma unroll
            for (int t = 0; t < 8; ++t) {
                floatx4 wq = *(const floatx4*)&Ws[i*H + t*16 + q*4];
                base1C[t].xy = fma2(c, wq.xy, base1C[t].xy);
                base1C[t].zw = fma2(c, wq.zw, base1C[t].zw);
            }
        }
    }
    __syncthreads();   // all lanes done reading W1 fp32 before repack

    // ---- pack W2 -> bf16 A-frags with pi-permuted k
    for (int ch = tid; ch < 2048; ch += 256) {
        int ln = ch & 63, ts = ch >> 6;
        int s = ts & 3, t = ts >> 2;
        int qq = ln >> 4, n = t*16 + (ln & 15);
        int u0 = s*32 + qq*4, u1 = u0 + 16;
        unsigned w0 = f2bf(W2[(u0+0)*H+n]) | (f2bf(W2[(u0+1)*H+n]) << 16);
        unsigned w1 = f2bf(W2[(u0+2)*H+n]) | (f2bf(W2[(u0+3)*H+n]) << 16);
        unsigned w2 = f2bf(W2[(u1+0)*H+n]) | (f2bf(W2[(u1+1)*H+n]) << 16);
        unsigned w3v = f2bf(W2[(u1+2)*H+n]) | (f2bf(W2[(u1+3)*H+n]) << 16);
        WbufU[ch] = make_uint4(w0, w1, w2, w3v);
    }

    // ---- per-lane point state
    float px_ = pos[p*3+0], py_ = pos[p*3+1], pz_ = pos[p*3+2];
    float tc_ = t1g[p];
    float off_ = tc_ - t2g[p];
    float D[9];
    #pragma unroll
    for (int j = 0; j < 9; ++j) D[j] = (j==0||j==4||j==8) ? 1.0f : 0.0f;
    const float b30 = b3[0], b31 = b3[1], b32 = b3[2];
    __syncthreads();

    const short8* Bf   = (const short8*)WbufU;
    const short8* W1Af = (const short8*)W1AU;
    const short8* W3Af = (const short8*)W3AU;
    const floatx4 Z4 = {0.f, 0.f, 0.f, 0.f};

    for (int step = 0; step < NSTEPS; ++step) {
        // ======== eval A: v(x,t) ========
        float vAx, vAy, vAz;
        {
            short8 xf = xyzt_frag(px_, py_, pz_, tc_, q);
            floatx4 z[8];
            #pragma unroll
            for (int t = 0; t < 8; ++t)
                z[t] = __builtin_amdgcn_mfma_f32_16x16x32_bf16(W1Af[t*64 + L], xf, base1C[t], 0, 0, 0);
            // (no sched_barrier: let frag build consume z[t] as MFMAs retire)
            short8 fh[4];
            #pragma unroll
            for (int s = 0; s < 4; ++s) {
                f32x2 a0 = tanh2(z[2*s].xy),   a1 = tanh2(z[2*s].zw);
                f32x2 c0 = tanh2(z[2*s+1].xy), c1 = tanh2(z[2*s+1].zw);
                fh[s] = mk8(pkv(a0), pkv(a1), pkv(c0), pkv(c1));
            }
            __builtin_amdgcn_sched_barrier(0);
            // quarter qi covers tiles 2qi,2qi+1 == L3 slice qi
            floatx4 vacc = Z4;
            #pragma unroll
            for (int qi = 0; qi < 4; ++qi) {
                const int T0 = 2*qi, T1 = 2*qi + 1;
                floatx4 acc0 = __builtin_amdgcn_mfma_f32_16x16x32_bf16(
                    Bf[(T0*4 + 0)*64 + L], fh[0], b2C4[T0*4 + q], 0, 0, 0);
                floatx4 acc1 = __builtin_amdgcn_mfma_f32_16x16x32_bf16(
                    Bf[(T1*4 + 0)*64 + L], fh[0], b2C4[T1*4 + q], 0, 0, 0);
                #pragma unroll
                for (int s = 1; s < 4; ++s) {
                    acc0 = __builtin_amdgcn_mfma_f32_16x16x32_bf16(Bf[(T0*4 + s)*64 + L], fh[s], acc0, 0, 0, 0);
                    acc1 = __builtin_amdgcn_mfma_f32_16x16x32_bf16(Bf[(T1*4 + s)*64 + L], fh[s], acc1, 0, 0, 0);
                }
                __builtin_amdgcn_sched_barrier(0);
                f32x2 e00 = tanh2(acc0.xy), e01 = tanh2(acc0.zw);
                f32x2 e10 = tanh2(acc1.xy), e11 = tanh2(acc1.zw);
                short8 ef = mk8(pkv(e00), pkv(e01), pkv(e10), pkv(e11));
                vacc = __builtin_amdgcn_mfma_f32_16x16x32_bf16(W3Af[qi*64 + L], ef, vacc, 0, 0, 0);
                __builtin_amdgcn_sched_barrier(0);
            }
            vAx = __shfl(vacc[0], m, 64);
            vAy = __shfl(vacc[1], m, 64);
            vAz = __shfl(vacc[2], m, 64);
        }

        float dt_ = copysignf(fminf(fabsf(off_), DT_MAXF), off_);
        float hd = 0.5f * dt_;
        float mx = px_ - hd*(vAx + b30);
        float my = py_ - hd*(vAy + b31);
        float mz = pz_ - hd*(vAz + b32);
        float tm = tc_ - hd;

        // ======== eval B: v + Jacobian at midpoint ========
        float vx, vy, vz, Jr[9];
        {
            short8 xf = xyzt_frag(mx, my, mz, tm, q);
            floatx4 z[8];
            #pragma unroll
            for (int t = 0; t < 8; ++t)
                z[t] = __builtin_amdgcn_mfma_f32_16x16x32_bf16(W1Af[t*64 + L], xf, base1C[t], 0, 0, 0);
            // (no sched_barrier: frag build may start as z[t] retire)
            short8 fh[4], fd0[4], fd1[4], fd2[4];
            #pragma unroll
            for (int s = 0; s < 4; ++s) {
                unsigned uh[4], u0[4], u1[4], u2[4];
                #pragma unroll
                for (int hf = 0; hf < 2; ++hf) {
                    int t = 2*s + hf;
                    f32x2 h0 = tanh2(z[t].xy), h1 = tanh2(z[t].zw);
                    f32x2 s0 = fma2(-h0, h0, sp2(1.0f));
                    f32x2 s1 = fma2(-h1, h1, sp2(1.0f));
                    floatx4 wx = WdX4[t*4 + q], wy = WdY4[t*4 + q], wz = WdZ4[t*4 + q];
                    uh[2*hf+0] = pkv(h0);         uh[2*hf+1] = pkv(h1);
                    u0[2*hf+0] = pkv(s0 * wx.xy); u0[2*hf+1] = pkv(s1 * wx.zw);
                    u1[2*hf+0] = pkv(s0 * wy.xy); u1[2*hf+1] = pkv(s1 * wy.zw);
                    u2[2*hf+0] = pkv(s0 * wz.xy); u2[2*hf+1] = pkv(s1 * wz.zw);
                }
                fh[s]  = mk8(uh[0], uh[1], uh[2], uh[3]);
                fd0[s] = mk8(u0[0], u0[1], u0[2], u0[3]);
                fd1[s] = mk8(u1[0], u1[1], u1[2], u1[3]);
                fd2[s] = mk8(u2[0], u2[1], u2[2], u2[3]);
            }
            __builtin_amdgcn_sched_barrier(0);
            // quarter qi = one L3 slice: tiles 2qi,2qi+1, all 4 chains, post,
            // 4 L3 MFMAs. Acc live = 8 quads; s2 consumed in-quarter.
            floatx4 V = Z4, J0 = Z4, J1 = Z4, J2 = Z4;
            #pragma unroll
            for (int qi = 0; qi < 4; ++qi) {
                const int T0 = 2*qi, T1 = 2*qi + 1;
                floatx4 aH0, aH1, aD00, aD01, aD10, aD11, aD20, aD21;
                {
                    short8 A0 = Bf[(T0*4 + 0)*64 + L];
                    short8 A1 = Bf[(T1*4 + 0)*64 + L];
                    aH0  = __builtin_amdgcn_mfma_f32_16x16x32_bf16(A0, fh[0],  b2C4[T0*4 + q], 0, 0, 0);
                    aH1  = __builtin_amdgcn_mfma_f32_16x16x32_bf16(A1, fh[0],  b2C4[T1*4 + q], 0, 0, 0);
                    aD00 = __builtin_amdgcn_mfma_f32_16x16x32_bf16(A0, fd0[0], Z4, 0, 0, 0);
                    aD01 = __builtin_amdgcn_mfma_f32_16x16x32_bf16(A1, fd0[0], Z4, 0, 0, 0);
                    aD10 = __builtin_amdgcn_mfma_f32_16x16x32_bf16(A0, fd1[0], Z4, 0, 0, 0);
                    aD11 = __builtin_amdgcn_mfma_f32_16x16x32_bf16(A1, fd1[0], Z4, 0, 0, 0);
                    aD20 = __builtin_amdgcn_mfma_f32_16x16x32_bf16(A0, fd2[0], Z4, 0, 0, 0);
                    aD21 = __builtin_amdgcn_mfma_f32_16x16x32_bf16(A1, fd2[0], Z4, 0, 0, 0);
                }
                __builtin_amdgcn_sched_barrier(0);
                #pragma unroll
                for (int s = 1; s < 4; ++s) {
                    short8 A0 = Bf[(T0*4 + s)*64 + L];
                    short8 A1 = Bf[(T1*4 + s)*64 + L];
                    aH0  = __builtin_amdgcn_mfma_f32_16x16x32_bf16(A0, fh[s],  aH0,  0, 0, 0);
                    aH1  = __builtin_amdgcn_mfma_f32_16x16x32_bf16(A1, fh[s],  aH1,  0, 0, 0);
                    aD00 = __builtin_amdgcn_mfma_f32_16x16x32_bf16(A0, fd0[s], aD00, 0, 0, 0);
                    aD01 = __builtin_amdgcn_mfma_f32_16x16x32_bf16(A1, fd0[s], aD01, 0, 0, 0);
                    aD10 = __builtin_amdgcn_mfma_f32_16x16x32_bf16(A0, fd1[s], aD10, 0, 0, 0);
                    aD11 = __builtin_amdgcn_mfma_f32_16x16x32_bf16(A1, fd1[s], aD11, 0, 0, 0);
                    aD20 = __builtin_amdgcn_mfma_f32_16x16x32_bf16(A0, fd2[s], aD20, 0, 0, 0);
                    aD21 = __builtin_amdgcn_mfma_f32_16x16x32_bf16(A1, fd2[s], aD21, 0, 0, 0);
                    __builtin_amdgcn_sched_barrier(0);
                }
                // post for this slice: h2/s2/dd -> e-frags -> 4 L3 MFMAs
                f32x2 h0 = tanh2(aH0.xy), h1 = tanh2(aH0.zw);
                f32x2 h2v = tanh2(aH1.xy), h3 = tanh2(aH1.zw);
                f32x2 s0 = fma2(-h0, h0, sp2(1.0f));
                f32x2 s1 = fma2(-h1, h1, sp2(1.0f));
                f32x2 s2v = fma2(-h2v, h2v, sp2(1.0f));
                f32x2 s3 = fma2(-h3, h3, sp2(1.0f));
                short8 eh = mk8(pkv(h0), pkv(h1), pkv(h2v), pkv(h3));
                short8 e0 = mk8(pkv(s0*aD00.xy), pkv(s1*aD00.zw), pkv(s2v*aD01.xy), pkv(s3*aD01.zw));
                short8 e1 = mk8(pkv(s0*aD10.xy), pkv(s1*aD10.zw), pkv(s2v*aD11.xy), pkv(s3*aD11.zw));
                short8 e2 = mk8(pkv(s0*aD20.xy), pkv(s1*aD20.zw), pkv(s2v*aD21.xy), pkv(s3*aD21.zw));
                const short8 WA = W3Af[qi*64 + L];
                V  = __builtin_amdgcn_mfma_f32_16x16x32_bf16(WA, eh, V,  0, 0, 0);
                J0 = __builtin_amdgcn_mfma_f32_16x16x32_bf16(WA, e0, J0, 0, 0, 0);
                J1 = __builtin_amdgcn_mfma_f32_16x16x32_bf16(WA, e1, J1, 0, 0, 0);
                J2 = __builtin_amdgcn_mfma_f32_16x16x32_bf16(WA, e2, J2, 0, 0, 0);
                __builtin_amdgcn_sched_barrier(0);
            }
            vx = __shfl(V[0], m, 64) + b30;
            vy = __shfl(V[1], m, 64) + b31;
            vz = __shfl(V[2], m, 64) + b32;
            Jr[0] = __shfl(J0[0], m, 64); Jr[1] = __shfl(J1[0], m, 64); Jr[2] = __shfl(J2[0], m, 64);
            Jr[3] = __shfl(J0[1], m, 64); Jr[4] = __shfl(J1[1], m, 64); Jr[5] = __shfl(J2[1], m, 64);
            Jr[6] = __shfl(J0[2], m, 64); Jr[7] = __shfl(J1[2], m, 64); Jr[8] = __shfl(J2[2], m, 64);
        }

        // def + state update, replicated identically in all lanes (inputs broadcast)
        float nd[9];
        #pragma unroll
        for (int o = 0; o < 3; ++o)
            #pragma unroll
            for (int c = 0; c < 3; ++c)
                nd[o*3+c] = D[o*3+c] - dt_*(Jr[o*3+0]*D[0*3+c] + Jr[o*3+1]*D[1*3+c] + Jr[o*3+2]*D[2*3+c]);
        #pragma unroll
        for (int j = 0; j < 9; ++j) D[j] = nd[j];
        px_ = fmaf(-dt_, vx, px_);
        py_ = fmaf(-dt_, vy, py_);
        pz_ = fmaf(-dt_, vz, pz_);
        tc_  -= dt_;
        off_ -= dt_;
    }

    // ---- output: q==0 lane of each point writes xyz + deform
    if (q == 0) {
        out[p*3+0] = px_; out[p*3+1] = py_; out[p*3+2] = pz_;
        float* o9 = out + (size_t)N*3 + (size_t)p*9;
        #pragma unroll
        for (int j = 0; j < 9; ++j) o9[j] = D[j];
    }
}

extern "C" void kernel_launch(void* const* d_in, const int* in_sizes, int n_in,
                              void* d_out, int out_size, void* d_ws, size_t ws_size,
                              hipStream_t stream) {
    const float* code = (const float*)d_in[0];
    const float* pos  = (const float*)d_in[1];
    const float* t1   = (const float*)d_in[2];
    const float* t2   = (const float*)d_in[3];
    const float* W1   = (const float*)d_in[4];
    const float* b1   = (const float*)d_in[5];
    const float* W2   = (const float*)d_in[6];
    const float* b2   = (const float*)d_in[7];
    const float* W3   = (const float*)d_in[8];
    const float* b3   = (const float*)d_in[9];
    float* out = (float*)d_out;
    const int N = in_sizes[1] / 3;           // 131072
    const int blocks = N / PPB;              // 2048
    velwarp<<<blocks, 256, 0, stream>>>(code, pos, t1, t2, W1, b1, W2, b2, W3, b3, out, N);
}

// Round 8
// 395.373 us; speedup vs baseline: 1.0493x; 1.0137x over previous
//
#include <hip/hip_runtime.h>
#include <hip/hip_bf16.h>

#define H 128
#define NSTEPS 8
#define DT_MAXF 0.125f
#define WAVES 4
#define PPW 16            // points per wave (one 16x16 MFMA N-tile)
#define PPB (WAVES*PPW)   // 64 points per block

typedef __attribute__((ext_vector_type(8))) short short8;   // 8 bf16 MFMA A/B frag
typedef __attribute__((ext_vector_type(4))) float floatx4;  // MFMA C/D frag
typedef __attribute__((ext_vector_type(2))) float f32x2;    // packed-FP32 pair (v_pk_*_f32)

__device__ __forceinline__ f32x2 sp2(float v) { return (f32x2){v, v}; }
__device__ __forceinline__ f32x2 fma2(f32x2 a, f32x2 b, f32x2 c) {
    return __builtin_elementwise_fma(a, b, c);              // -> v_pk_fma_f32
}
// tanh pair, MERGED-rcp form (R17): e=exp2(2log2e*x); 1/(ea+1) = (eb+1)*rcp((ea+1)(eb+1)).
// One v_rcp instead of two (trans are quarter-rate); the half-swap is a free
// VOP3P op_sel. <=2ulp f32 vs the old form, ahead of bf16 rounding.
__device__ __forceinline__ f32x2 tanh2(f32x2 x) {
    f32x2 y = x * 2.8853900817779268f;
    f32x2 e; e[0] = __builtin_amdgcn_exp2f(y[0]); e[1] = __builtin_amdgcn_exp2f(y[1]);
    f32x2 ep = e + 1.0f;
    float rt = __builtin_amdgcn_rcpf(ep[0] * ep[1]);
    f32x2 eps = __builtin_shufflevector(ep, ep, 1, 0);
    f32x2 r = eps * sp2(rt);
    return fma2(sp2(-2.0f), r, sp2(1.0f));
}
__device__ __forceinline__ unsigned f2bf(float x) {           // fp32 -> bf16 bits, RNE
    unsigned u = __float_as_uint(x);
    return (u + 0x7FFFu + ((u >> 16) & 1u)) >> 16;
}
__device__ __forceinline__ unsigned pk2(float a, float b) {   // packed bf16 cvt
    union { __hip_bfloat162 h; unsigned u; } U;
    U.h = __float22bfloat162_rn(make_float2(a, b));
    return U.u;
}
__device__ __forceinline__ unsigned pkv(f32x2 v) { return pk2(v[0], v[1]); }
__device__ __forceinline__ short8 mk8(unsigned a, unsigned b, unsigned c, unsigned d) {
    union { unsigned u[4]; short8 s; } U;
    U.u[0] = a; U.u[1] = b; U.u[2] = c; U.u[3] = d; return U.s;
}
// xyzt B-frag, hi/lo split bf16. Lane q=0 carries hi+lo, q=1 carries hi, q>=2 zero.
__device__ __forceinline__ short8 xyzt_frag(float x, float y, float z, float t, int q) {
    unsigned hx = f2bf(x), hy = f2bf(y), hz = f2bf(z), ht = f2bf(t);
    float lx = x - __uint_as_float(hx << 16);
    float ly = y - __uint_as_float(hy << 16);
    float lz = z - __uint_as_float(hz << 16);
    float lt = t - __uint_as_float(ht << 16);
    unsigned w0 = hx | (hy << 16), w1 = hz | (ht << 16);
    unsigned w2 = pk2(lx, ly),     w3 = pk2(lz, lt);
    union { unsigned u[4]; short8 s; } F;
    F.u[0] = (q < 2)  ? w0 : 0u;
    F.u[1] = (q < 2)  ? w1 : 0u;
    F.u[2] = (q == 0) ? w2 : 0u;
    F.u[3] = (q == 0) ? w3 : 0u;
    return F.s;
}

// R12: L1/L2/L3 on the MFMA pipe (pi-permuted k; zero cross-lane repack).
// R13-R16 occupancy arc: NULL -- 3 waves/SIMD gives the same VALUBusy/MfmaUtil
//   as 2 (R15); register file (arch+AGPR), not LDS, binds; forced budgets spill.
// R17: attack issued slots directly (VALUBusy*dur flat at ~24000 since R12):
//   (1) merged-rcp tanh2: -64 trans-issues/step (1 rcp + 2 pk-muls per pair).
//   (2) Jr broadcasts dropped: J rows 0-2 already live in the q==0 lane's
//       J0..J2 regs (q!=0 lanes see zero rows -> harmless local D). -9 bpermute
//       + shorter lgkm drain per step.
//   (3) D stored as 3x f32x2 + 3 floats; update packed (same per-element op
//       order -> bitwise identical). Position updates packed too.
//   (4) eval-B L2 nest: intra-quarter sched_barriers removed (quarter-boundary
//       ones kept -> hoisting capped at 8 Bf reads / 32 VGPRs; r9 ghost fenced).
// Guard: WRITE_SIZE ~6.1MB. Ballooning => (4) hoisted; revert next round.
__global__ __launch_bounds__(256, 2)
void velwarp(const float* __restrict__ code, const float* __restrict__ pos,
             const float* __restrict__ t1g, const float* __restrict__ t2g,
             const float* __restrict__ W1, const float* __restrict__ b1,
             const float* __restrict__ W2, const float* __restrict__ b2,
             const float* __restrict__ W3, const float* __restrict__ b3,
             float* __restrict__ out, int N)
{
    __shared__ __align__(16) uint4 WbufU[2048];   // 32KB: W1 fp32 staging (init) then W2 bf16 frags
    __shared__ __align__(16) uint4 W1AU[8*64];    // 8KB : layer-1 A-frags (xyzt rows, hi/lo split)
    __shared__ __align__(16) uint4 W3AU[4*64];    // 4KB : layer-3 A-frags (W3^T, pi-permuted)
    __shared__ __align__(16) floatx4 WdX4[32];    // W1[64][u] in C/D order (= row-linear)
    __shared__ __align__(16) floatx4 WdY4[32];    // W1[65][u]
    __shared__ __align__(16) floatx4 WdZ4[32];    // W1[66][u]
    __shared__ __align__(16) floatx4 b2C4[32];    // b2 in C/D order

    const int tid = threadIdx.x;
    const int L   = tid & 63;
    const int m   = L & 15;      // this lane's point (C/D col)
    const int q   = L >> 4;      // C/D row group = q*4+reg; B-frag k-quad
    const int pb  = blockIdx.x * PPB + (tid >> 6) * PPW;
    const int p   = pb + m;      // global point index

    // ---- stage W1 rows [0:64) as fp32 into Wbuf
    {
        const float4* s4 = (const float4*)W1;
        float4* d4 = (float4*)WbufU;
        #pragma unroll 4
        for (int i = tid; i < (64*H)/4; i += 256) d4[i] = s4[i];
    }
    // ---- layer-1 A-frags: tile t, lane l: row u = 16t+(l&15); hi/lo split
    for (int e = tid; e < 512; e += 256) {
        int t = e >> 6, l = e & 63;
        int u = t*16 + (l & 15), qq = l >> 4;
        unsigned hb[4], lb[4];
        #pragma unroll
        for (int c = 0; c < 4; ++c) {
            float wv = W1[(64 + c)*H + u];
            unsigned hh = f2bf(wv);
            float wl = wv - __uint_as_float(hh << 16);
            hb[c] = hh; lb[c] = f2bf(wl);
        }
        unsigned hi01 = hb[0] | (hb[1] << 16), hi23 = hb[2] | (hb[3] << 16);
        unsigned lo01 = lb[0] | (lb[1] << 16), lo23 = lb[2] | (lb[3] << 16);
        uint4 o;
        if (qq == 0)      o = make_uint4(hi01, hi23, hi01, hi23);
        else if (qq == 1) o = make_uint4(lo01, lo23, 0u, 0u);
        else              o = make_uint4(0u, 0u, 0u, 0u);
        W1AU[e] = o;
    }
    // ---- layer-3 A-frags: slice s, lane l: row a = l&15 (rows 3..15 zero)
    for (int e = tid; e < 256; e += 256) {
        int s = e >> 6, l = e & 63;
        int a = l & 15, qq = l >> 4;
        uint4 o = make_uint4(0u, 0u, 0u, 0u);
        if (a < 3) {
            int u0 = s*32 + qq*4, u1 = u0 + 16;
            o.x = f2bf(W3[(u0+0)*3+a]) | (f2bf(W3[(u0+1)*3+a]) << 16);
            o.y = f2bf(W3[(u0+2)*3+a]) | (f2bf(W3[(u0+3)*3+a]) << 16);
            o.z = f2bf(W3[(u1+0)*3+a]) | (f2bf(W3[(u1+1)*3+a]) << 16);
            o.w = f2bf(W3[(u1+2)*3+a]) | (f2bf(W3[(u1+3)*3+a]) << 16);
        }
        W3AU[e] = o;
    }
    if (tid < 32) {
        WdX4[tid] = ((const floatx4*)(W1 + (size_t)64*H))[tid];
        WdY4[tid] = ((const floatx4*)(W1 + (size_t)65*H))[tid];
        WdZ4[tid] = ((const floatx4*)(W1 + (size_t)66*H))[tid];
        b2C4[tid] = ((const floatx4*)b2)[tid];
    }
    __syncthreads();

    // ---- base1C[t] (fp32, C/D layout): u = 16t + 4q + reg
    floatx4 base1C[8];
    {
        #pragma unroll
        for (int t = 0; t < 8; ++t) base1C[t] = *(const floatx4*)&b1[t*16 + q*4];
        const float* Ws = (const float*)WbufU;
        const float* crow = code + (size_t)p * 64;
        for (int i = 0; i < 64; ++i) {
            f32x2 c = sp2(crow[i]);
            #pragma unroll
            for (int t = 0; t < 8; ++t) {
                floatx4 wq = *(const floatx4*)&Ws[i*H + t*16 + q*4];
                base1C[t].xy = fma2(c, wq.xy, base1C[t].xy);
                base1C[t].zw = fma2(c, wq.zw, base1C[t].zw);
            }
        }
    }
    __syncthreads();   // all lanes done reading W1 fp32 before repack

    // ---- pack W2 -> bf16 A-frags with pi-permuted k
    for (int ch = tid; ch < 2048; ch += 256) {
        int ln = ch & 63, ts = ch >> 6;
        int s = ts & 3, t = ts >> 2;
        int qq = ln >> 4, n = t*16 + (ln & 15);
        int u0 = s*32 + qq*4, u1 = u0 + 16;
        unsigned w0 = f2bf(W2[(u0+0)*H+n]) | (f2bf(W2[(u0+1)*H+n]) << 16);
        unsigned w1 = f2bf(W2[(u0+2)*H+n]) | (f2bf(W2[(u0+3)*H+n]) << 16);
        unsigned w2 = f2bf(W2[(u1+0)*H+n]) | (f2bf(W2[(u1+1)*H+n]) << 16);
        unsigned w3v = f2bf(W2[(u1+2)*H+n]) | (f2bf(W2[(u1+3)*H+n]) << 16);
        WbufU[ch] = make_uint4(w0, w1, w2, w3v);
    }

    // ---- per-lane point state
    float px_ = pos[p*3+0], py_ = pos[p*3+1], pz_ = pos[p*3+2];
    float tc_ = t1g[p];
    float off_ = tc_ - t2g[p];
    // deform D as 3 packed col-pairs + 3 scalars (cols 0,1 | col 2), row o
    f32x2 Dp[3]; float Ds[3];
    Dp[0] = (f32x2){1.f, 0.f}; Ds[0] = 0.f;
    Dp[1] = (f32x2){0.f, 1.f}; Ds[1] = 0.f;
    Dp[2] = (f32x2){0.f, 0.f}; Ds[2] = 1.f;
    const float b30 = b3[0], b31 = b3[1], b32 = b3[2];
    __syncthreads();

    const short8* Bf   = (const short8*)WbufU;
    const short8* W1Af = (const short8*)W1AU;
    const short8* W3Af = (const short8*)W3AU;
    const floatx4 Z4 = {0.f, 0.f, 0.f, 0.f};

    for (int step = 0; step < NSTEPS; ++step) {
        // ======== eval A: v(x,t) ========
        float vAx, vAy, vAz;
        {
            short8 xf = xyzt_frag(px_, py_, pz_, tc_, q);
            floatx4 z[8];
            #pragma unroll
            for (int t = 0; t < 8; ++t)
                z[t] = __builtin_amdgcn_mfma_f32_16x16x32_bf16(W1Af[t*64 + L], xf, base1C[t], 0, 0, 0);
            short8 fh[4];
            #pragma unroll
            for (int s = 0; s < 4; ++s) {
                f32x2 a0 = tanh2(z[2*s].xy),   a1 = tanh2(z[2*s].zw);
                f32x2 c0 = tanh2(z[2*s+1].xy), c1 = tanh2(z[2*s+1].zw);
                fh[s] = mk8(pkv(a0), pkv(a1), pkv(c0), pkv(c1));
            }
            __builtin_amdgcn_sched_barrier(0);
            // quarter qi covers tiles 2qi,2qi+1 == L3 slice qi
            floatx4 vacc = Z4;
            #pragma unroll
            for (int qi = 0; qi < 4; ++qi) {
                const int T0 = 2*qi, T1 = 2*qi + 1;
                floatx4 acc0 = __builtin_amdgcn_mfma_f32_16x16x32_bf16(
                    Bf[(T0*4 + 0)*64 + L], fh[0], b2C4[T0*4 + q], 0, 0, 0);
                floatx4 acc1 = __builtin_amdgcn_mfma_f32_16x16x32_bf16(
                    Bf[(T1*4 + 0)*64 + L], fh[0], b2C4[T1*4 + q], 0, 0, 0);
                #pragma unroll
                for (int s = 1; s < 4; ++s) {
                    acc0 = __builtin_amdgcn_mfma_f32_16x16x32_bf16(Bf[(T0*4 + s)*64 + L], fh[s], acc0, 0, 0, 0);
                    acc1 = __builtin_amdgcn_mfma_f32_16x16x32_bf16(Bf[(T1*4 + s)*64 + L], fh[s], acc1, 0, 0, 0);
                }
                f32x2 e00 = tanh2(acc0.xy), e01 = tanh2(acc0.zw);
                f32x2 e10 = tanh2(acc1.xy), e11 = tanh2(acc1.zw);
                short8 ef = mk8(pkv(e00), pkv(e01), pkv(e10), pkv(e11));
                vacc = __builtin_amdgcn_mfma_f32_16x16x32_bf16(W3Af[qi*64 + L], ef, vacc, 0, 0, 0);
                __builtin_amdgcn_sched_barrier(0);
            }
            vAx = __shfl(vacc[0], m, 64);
            vAy = __shfl(vacc[1], m, 64);
            vAz = __shfl(vacc[2], m, 64);
        }

        float dt_ = copysignf(fminf(fabsf(off_), DT_MAXF), off_);
        float hd = 0.5f * dt_;
        float mx = px_ - hd*(vAx + b30);
        float my = py_ - hd*(vAy + b31);
        float mz = pz_ - hd*(vAz + b32);
        float tm = tc_ - hd;

        // ======== eval B: v + Jacobian at midpoint ========
        float vx, vy, vz;
        floatx4 V = Z4, J0 = Z4, J1 = Z4, J2 = Z4;
        {
            short8 xf = xyzt_frag(mx, my, mz, tm, q);
            floatx4 z[8];
            #pragma unroll
            for (int t = 0; t < 8; ++t)
                z[t] = __builtin_amdgcn_mfma_f32_16x16x32_bf16(W1Af[t*64 + L], xf, base1C[t], 0, 0, 0);
            short8 fh[4], fd0[4], fd1[4], fd2[4];
            #pragma unroll
            for (int s = 0; s < 4; ++s) {
                unsigned uh[4], u0[4], u1[4], u2[4];
                #pragma unroll
                for (int hf = 0; hf < 2; ++hf) {
                    int t = 2*s + hf;
                    f32x2 h0 = tanh2(z[t].xy), h1 = tanh2(z[t].zw);
                    f32x2 s0 = fma2(-h0, h0, sp2(1.0f));
                    f32x2 s1 = fma2(-h1, h1, sp2(1.0f));
                    floatx4 wx = WdX4[t*4 + q], wy = WdY4[t*4 + q], wz = WdZ4[t*4 + q];
                    uh[2*hf+0] = pkv(h0);         uh[2*hf+1] = pkv(h1);
                    u0[2*hf+0] = pkv(s0 * wx.xy); u0[2*hf+1] = pkv(s1 * wx.zw);
                    u1[2*hf+0] = pkv(s0 * wy.xy); u1[2*hf+1] = pkv(s1 * wy.zw);
                    u2[2*hf+0] = pkv(s0 * wz.xy); u2[2*hf+1] = pkv(s1 * wz.zw);
                }
                fh[s]  = mk8(uh[0], uh[1], uh[2], uh[3]);
                fd0[s] = mk8(u0[0], u0[1], u0[2], u0[3]);
                fd1[s] = mk8(u1[0], u1[1], u1[2], u1[3]);
                fd2[s] = mk8(u2[0], u2[1], u2[2], u2[3]);
            }
            __builtin_amdgcn_sched_barrier(0);
            // quarter qi = one L3 slice: tiles 2qi,2qi+1, all 4 chains, post,
            // 4 L3 MFMAs. Intra-quarter barriers removed (R17); quarter-end kept.
            #pragma unroll
            for (int qi = 0; qi < 4; ++qi) {
                const int T0 = 2*qi, T1 = 2*qi + 1;
                floatx4 aH0, aH1, aD00, aD01, aD10, aD11, aD20, aD21;
                {
                    short8 A0 = Bf[(T0*4 + 0)*64 + L];
                    short8 A1 = Bf[(T1*4 + 0)*64 + L];
                    aH0  = __builtin_amdgcn_mfma_f32_16x16x32_bf16(A0, fh[0],  b2C4[T0*4 + q], 0, 0, 0);
                    aH1  = __builtin_amdgcn_mfma_f32_16x16x32_bf16(A1, fh[0],  b2C4[T1*4 + q], 0, 0, 0);
                    aD00 = __builtin_amdgcn_mfma_f32_16x16x32_bf16(A0, fd0[0], Z4, 0, 0, 0);
                    aD01 = __builtin_amdgcn_mfma_f32_16x16x32_bf16(A1, fd0[0], Z4, 0, 0, 0);
                    aD10 = __builtin_amdgcn_mfma_f32_16x16x32_bf16(A0, fd1[0], Z4, 0, 0, 0);
                    aD11 = __builtin_amdgcn_mfma_f32_16x16x32_bf16(A1, fd1[0], Z4, 0, 0, 0);
                    aD20 = __builtin_amdgcn_mfma_f32_16x16x32_bf16(A0, fd2[0], Z4, 0, 0, 0);
                    aD21 = __builtin_amdgcn_mfma_f32_16x16x32_bf16(A1, fd2[0], Z4, 0, 0, 0);
                }
                #pragma unroll
                for (int s = 1; s < 4; ++s) {
                    short8 A0 = Bf[(T0*4 + s)*64 + L];
                    short8 A1 = Bf[(T1*4 + s)*64 + L];
                    aH0  = __builtin_amdgcn_mfma_f32_16x16x32_bf16(A0, fh[s],  aH0,  0, 0, 0);
                    aH1  = __builtin_amdgcn_mfma_f32_16x16x32_bf16(A1, fh[s],  aH1,  0, 0, 0);
                    aD00 = __builtin_amdgcn_mfma_f32_16x16x32_bf16(A0, fd0[s], aD00, 0, 0, 0);
                    aD01 = __builtin_amdgcn_mfma_f32_16x16x32_bf16(A1, fd0[s], aD01, 0, 0, 0);
                    aD10 = __builtin_amdgcn_mfma_f32_16x16x32_bf16(A0, fd1[s], aD10, 0, 0, 0);
                    aD11 = __builtin_amdgcn_mfma_f32_16x16x32_bf16(A1, fd1[s], aD11, 0, 0, 0);
                    aD20 = __builtin_amdgcn_mfma_f32_16x16x32_bf16(A0, fd2[s], aD20, 0, 0, 0);
                    aD21 = __builtin_amdgcn_mfma_f32_16x16x32_bf16(A1, fd2[s], aD21, 0, 0, 0);
                }
                // post for this slice: h2/s2/dd -> e-frags -> 4 L3 MFMAs
                f32x2 h0 = tanh2(aH0.xy), h1 = tanh2(aH0.zw);
                f32x2 h2v = tanh2(aH1.xy), h3 = tanh2(aH1.zw);
                f32x2 s0 = fma2(-h0, h0, sp2(1.0f));
                f32x2 s1 = fma2(-h1, h1, sp2(1.0f));
                f32x2 s2v = fma2(-h2v, h2v, sp2(1.0f));
                f32x2 s3 = fma2(-h3, h3, sp2(1.0f));
                short8 eh = mk8(pkv(h0), pkv(h1), pkv(h2v), pkv(h3));
                short8 e0 = mk8(pkv(s0*aD00.xy), pkv(s1*aD00.zw), pkv(s2v*aD01.xy), pkv(s3*aD01.zw));
                short8 e1 = mk8(pkv(s0*aD10.xy), pkv(s1*aD10.zw), pkv(s2v*aD11.xy), pkv(s3*aD11.zw));
                short8 e2 = mk8(pkv(s0*aD20.xy), pkv(s1*aD20.zw), pkv(s2v*aD21.xy), pkv(s3*aD21.zw));
                const short8 WA = W3Af[qi*64 + L];
                V  = __builtin_amdgcn_mfma_f32_16x16x32_bf16(WA, eh, V,  0, 0, 0);
                J0 = __builtin_amdgcn_mfma_f32_16x16x32_bf16(WA, e0, J0, 0, 0, 0);
                J1 = __builtin_amdgcn_mfma_f32_16x16x32_bf16(WA, e1, J1, 0, 0, 0);
                J2 = __builtin_amdgcn_mfma_f32_16x16x32_bf16(WA, e2, J2, 0, 0, 0);
                __builtin_amdgcn_sched_barrier(0);
            }
            vx = __shfl(V[0], m, 64) + b30;
            vy = __shfl(V[1], m, 64) + b31;
            vz = __shfl(V[2], m, 64) + b32;
            // Jr stays LOCAL: point m's Jacobian rows live in its q==0 lane's
            // J0..J2 regs 0..2 (other q-lanes hold zero rows -> harmless D).
        }

        // def + state update. J{k}[o] = dJ_o/dx_k (valid on q==0; 0 elsewhere).
        {
            f32x2 ndp[3]; float nds[3];
            #pragma unroll
            for (int o = 0; o < 3; ++o) {
                f32x2 tp = J0[o] * Dp[0];
                tp = fma2(sp2(J1[o]), Dp[1], tp);
                tp = fma2(sp2(J2[o]), Dp[2], tp);
                ndp[o] = fma2(sp2(-dt_), tp, Dp[o]);
                float ts = J0[o]*Ds[0];
                ts = fmaf(J1[o], Ds[1], ts);
                ts = fmaf(J2[o], Ds[2], ts);
                nds[o] = fmaf(-dt_, ts, Ds[o]);
            }
            #pragma unroll
            for (int o = 0; o < 3; ++o) { Dp[o] = ndp[o]; Ds[o] = nds[o]; }
        }
        px_ = fmaf(-dt_, vx, px_);
        py_ = fmaf(-dt_, vy, py_);
        pz_ = fmaf(-dt_, vz, pz_);
        tc_  -= dt_;
        off_ -= dt_;
    }

    // ---- output: q==0 lane of each point writes xyz + deform
    if (q == 0) {
        out[p*3+0] = px_; out[p*3+1] = py_; out[p*3+2] = pz_;
        float* o9 = out + (size_t)N*3 + (size_t)p*9;
        #pragma unroll
        for (int o = 0; o < 3; ++o) {
            o9[o*3+0] = Dp[o][0];
            o9[o*3+1] = Dp[o][1];
            o9[o*3+2] = Ds[o];
        }
    }
}

extern "C" void kernel_launch(void* const* d_in, const int* in_sizes, int n_in,
                              void* d_out, int out_size, void* d_ws, size_t ws_size,
                              hipStream_t stream) {
    const float* code = (const float*)d_in[0];
    const float* pos  = (const float*)d_in[1];
    const float* t1   = (const float*)d_in[2];
    const float* t2   = (const float*)d_in[3];
    const float* W1   = (const float*)d_in[4];
    const float* b1   = (const float*)d_in[5];
    const float* W2   = (const float*)d_in[6];
    const float* b2   = (const float*)d_in[7];
    const float* W3   = (const float*)d_in[8];
    const float* b3   = (const float*)d_in[9];
    float* out = (float*)d_out;
    const int N = in_sizes[1] / 3;           // 131072
    const int blocks = N / PPB;              // 2048
    velwarp<<<blocks, 256, 0, stream>>>(code, pos, t1, t2, W1, b1, W2, b2, W3, b3, out, N);
}